// Round 18
// baseline (250.506 us; speedup 1.0000x reference)
//
#include <hip/hip_runtime.h>
#include <math.h>

#define L2E 1.44269504088896f
#define LRELU(v) fmaxf((v), 0.2f * (v))

__device__ __forceinline__ float fexp2(float v) { return __builtin_amdgcn_exp2f(v); }
// fast ELU: exp(r)-1 via v_exp_f32 (vs ~30-inst libm expm1f)
__device__ __forceinline__ float felu(float r) {
    return r > 0.f ? r : fexp2(r * L2E) - 1.f;
}

// bf16 helpers (RNE pack, exact unpack)
__device__ __forceinline__ unsigned short f2bf(float f) {
    unsigned u = __float_as_uint(f);
    u += 0x7FFFu + ((u >> 16) & 1u);
    return (unsigned short)(u >> 16);
}
__device__ __forceinline__ float bf2f(unsigned short b) {
    return __uint_as_float((unsigned)b << 16);
}

typedef __attribute__((ext_vector_type(8))) short bf16x8;
typedef __attribute__((ext_vector_type(4))) float f32x4;

// base-2 online-softmax update, 8 channels packed in uint4 (bf16 pairs)
#define UPD8(mm, dd, Aa, Ab, ev, U)                                       \
    {                                                                     \
        float mn_ = fmaxf(mm, ev);                                        \
        float sc_ = fexp2(mm - mn_);                                      \
        float w_  = fexp2(ev - mn_);                                      \
        dd = dd * sc_ + w_;                                               \
        Aa.x = Aa.x * sc_ + w_ * __uint_as_float((U).x << 16);            \
        Aa.y = Aa.y * sc_ + w_ * __uint_as_float((U).x & 0xffff0000u);    \
        Aa.z = Aa.z * sc_ + w_ * __uint_as_float((U).y << 16);            \
        Aa.w = Aa.w * sc_ + w_ * __uint_as_float((U).y & 0xffff0000u);    \
        Ab.x = Ab.x * sc_ + w_ * __uint_as_float((U).z << 16);            \
        Ab.y = Ab.y * sc_ + w_ * __uint_as_float((U).z & 0xffff0000u);    \
        Ab.z = Ab.z * sc_ + w_ * __uint_as_float((U).w << 16);            \
        Ab.w = Ab.w * sc_ + w_ * __uint_as_float((U).w & 0xffff0000u);    \
        mm = mn_;                                                         \
    }
#define UPD1(mm, dd, aa, ev, hv)           \
    {                                      \
        float mn_ = fmaxf(mm, ev);         \
        float sc_ = fexp2(mm - mn_);       \
        float w_  = fexp2(ev - mn_);       \
        dd = dd * sc_ + w_;                \
        aa = aa * sc_ + w_ * (hv);         \
        mm = mn_;                          \
    }

#define CH 4096   // edges per histogram/scatter block

// ---------------- layer-1 GEMM via MFMA + FUSED alpha dots ----------------
// Wave = 16-node x 16-col tile. After the K-loop, lane (lg,lr) holds
// h1[n0+lg*4+r][c0+lr]; per-head alpha dots via 8-lane butterfly (masks 1,2,4
// stay within the lr<8 / lr>=8 halves). Lanes lr==0 / lr==8 write 4 rows each.
__global__ __launch_bounds__(256) void k_gemm1_mfma(
        const float* __restrict__ x, const float* __restrict__ W,
        const float* __restrict__ a_src, const float* __restrict__ a_dst,
        unsigned short* __restrict__ h1b, unsigned short* __restrict__ asrcb,
        float* __restrict__ adst1, int N, int ntiles) {
    int tid = threadIdx.x;
    int w = tid >> 6, l = tid & 63;
    int c0 = w * 16;
    int lr = l & 15;
    int lg = l >> 4;

    bf16x8 bfr[4];
#pragma unroll
    for (int kk = 0; kk < 4; ++kk)
#pragma unroll
        for (int j = 0; j < 8; ++j)
            bfr[kk][j] = (short)f2bf(W[(size_t)(kk * 32 + lg * 8 + j) * 64 + c0 + lr]);

    float asv = a_src[c0 + lr];   // per-lane alpha weights (col c0+lr)
    float adv = a_dst[c0 + lr];

    for (int t = blockIdx.x; t < ntiles; t += gridDim.x) {
        int n0 = t * 16;
        int n = n0 + lr;
        const float4* xr = (const float4*)(x + (size_t)(n < N ? n : 0) * 128);
        f32x4 acc = {0.f, 0.f, 0.f, 0.f};
#pragma unroll
        for (int kk = 0; kk < 4; ++kk) {
            float4 u0 = xr[kk * 8 + lg * 2];
            float4 u1 = xr[kk * 8 + lg * 2 + 1];
            bf16x8 afr;
            afr[0] = (short)f2bf(u0.x); afr[1] = (short)f2bf(u0.y);
            afr[2] = (short)f2bf(u0.z); afr[3] = (short)f2bf(u0.w);
            afr[4] = (short)f2bf(u1.x); afr[5] = (short)f2bf(u1.y);
            afr[6] = (short)f2bf(u1.z); afr[7] = (short)f2bf(u1.w);
            acc = __builtin_amdgcn_mfma_f32_16x16x32_bf16(afr, bfr[kk], acc, 0, 0, 0);
        }
        // h1 store
#pragma unroll
        for (int r = 0; r < 4; ++r) {
            int nn = n0 + lg * 4 + r;
            if (nn < N) h1b[(size_t)nn * 64 + c0 + lr] = f2bf(acc[r]);
        }
        // fused alpha dots: partials then 8-lane butterfly
        float ps[4], pd[4];
#pragma unroll
        for (int r = 0; r < 4; ++r) { ps[r] = acc[r] * asv; pd[r] = acc[r] * adv; }
#pragma unroll
        for (int mask = 1; mask <= 4; mask <<= 1)
#pragma unroll
            for (int r = 0; r < 4; ++r) {
                ps[r] += __shfl_xor(ps[r], mask);
                pd[r] += __shfl_xor(pd[r], mask);
            }
        if ((lr & 7) == 0) {
            int h = (c0 + lr) >> 3;   // 2w or 2w+1
#pragma unroll
            for (int r = 0; r < 4; ++r) {
                int nn = n0 + lg * 4 + r;
                if (nn < N) {
                    asrcb[nn * 8 + h] = f2bf(ps[r] * L2E);
                    adst1[nn * 8 + h] = pd[r] * L2E;
                }
            }
        }
    }
}

// ---------------- graph-bucket sort (zero global atomics, 4-way ILP) ----------------

__global__ __launch_bounds__(256) void k_bhist(const int* __restrict__ dstE,
                                               const int* __restrict__ batch,
                                               int E, int NB, int G, int* __restrict__ bh,
                                               int* __restrict__ done) {
    __shared__ int lh[512];
    int tid = threadIdx.x, b = blockIdx.x;
    if (b == 0 && tid == 0) *done = 0;   // reset last-block flag for k_mscan (replay-safe)
    lh[tid] = 0; lh[tid + 256] = 0;
    __syncthreads();
#pragma unroll
    for (int i = 0; i < CH / 1024; ++i) {
        int eb = b * CH + (i * 256 + tid) * 4;
        if (eb + 3 < E) {
            int4 dv = *(const int4*)(dstE + eb);
            int g0 = batch[dv.x], g1 = batch[dv.y], g2 = batch[dv.z], g3 = batch[dv.w];
            atomicAdd(&lh[g0], 1); atomicAdd(&lh[g1], 1);
            atomicAdd(&lh[g2], 1); atomicAdd(&lh[g3], 1);
        } else {
#pragma unroll
            for (int k = 0; k < 4; ++k)
                if (eb + k < E) atomicAdd(&lh[batch[dstE[eb + k]]], 1);
        }
    }
    __syncthreads();
    if (tid < G)       bh[(size_t)tid * NB + b] = lh[tid];
    if (tid + 256 < G) bh[(size_t)(tid + 256) * NB + b] = lh[tid + 256];
}

// per-bin exclusive scan across blocks; LAST block also scans totals -> boff
// and computes nstart[g] = lower_bound(batch, g).
__global__ __launch_bounds__(512) void k_mscan(const int* __restrict__ bh, int NB,
                                               int* __restrict__ pstart, int* __restrict__ total,
                                               int* __restrict__ boff, int* __restrict__ nstart,
                                               const int* __restrict__ batch, int N, int G,
                                               int* __restrict__ done) {
    __shared__ int buf[512];
    __shared__ int isLast;
    int bin = blockIdx.x, t = threadIdx.x;
    int v = (t < NB) ? bh[(size_t)bin * NB + t] : 0;
    buf[t] = v;
    __syncthreads();
    for (int off = 1; off < 512; off <<= 1) {
        int u = (t >= off) ? buf[t - off] : 0;
        __syncthreads();
        buf[t] += u;
        __syncthreads();
    }
    if (t < NB) pstart[(size_t)bin * NB + t] = buf[t] - v;
    if (t == 511) total[bin] = buf[511];
    // last-block-done: fold former k_scan_top in
    __threadfence();
    if (t == 0) isLast = (atomicAdd(done, 1) == (int)gridDim.x - 1) ? 1 : 0;
    __syncthreads();
    if (isLast) {
        int tv = (t < G) ? atomicAdd(&total[t], 0) : 0;   // coherent read
        buf[t] = tv;
        __syncthreads();
        for (int off = 1; off < 512; off <<= 1) {
            int u = (t >= off) ? buf[t - off] : 0;
            __syncthreads();
            buf[t] += u;
            __syncthreads();
        }
        if (t < G) {
            boff[t] = buf[t] - tv;
            int lo = 0, hi = N;
            while (lo < hi) { int mid = (lo + hi) >> 1; if (batch[mid] < t) lo = mid + 1; else hi = mid; }
            nstart[t] = lo;
        }
    }
}

// scatter edges into graph buckets as packed int: src | (local_dst << 17)
__global__ __launch_bounds__(256) void k_bscatter(const int* __restrict__ srcE,
                                                  const int* __restrict__ dstE,
                                                  const int* __restrict__ batch,
                                                  const int* __restrict__ boff,
                                                  const int* __restrict__ pstart,
                                                  const int* __restrict__ nstart,
                                                  int E, int NB, int G, int* __restrict__ pairs) {
    __shared__ int lstart[512];
    __shared__ int lc[512];
    __shared__ int lns[512];
    int tid = threadIdx.x, b = blockIdx.x;
#pragma unroll
    for (int j = tid; j < 512; j += 256) {
        lstart[j] = (j < G) ? boff[j] + pstart[(size_t)j * NB + b] : 0;
        lns[j] = (j < G) ? nstart[j] : 0;
        lc[j] = 0;
    }
    __syncthreads();
#pragma unroll
    for (int i = 0; i < CH / 1024; ++i) {
        int eb = b * CH + (i * 256 + tid) * 4;
        if (eb + 3 < E) {
            int4 sv = *(const int4*)(srcE + eb);
            int4 dv = *(const int4*)(dstE + eb);
            int g0 = batch[dv.x], g1 = batch[dv.y], g2 = batch[dv.z], g3 = batch[dv.w];
            int p0 = atomicAdd(&lc[g0], 1);
            int p1 = atomicAdd(&lc[g1], 1);
            int p2 = atomicAdd(&lc[g2], 1);
            int p3 = atomicAdd(&lc[g3], 1);
            pairs[lstart[g0] + p0] = sv.x | ((dv.x - lns[g0]) << 17);
            pairs[lstart[g1] + p1] = sv.y | ((dv.y - lns[g1]) << 17);
            pairs[lstart[g2] + p2] = sv.z | ((dv.z - lns[g2]) << 17);
            pairs[lstart[g3] + p3] = sv.w | ((dv.w - lns[g3]) << 17);
        } else {
#pragma unroll
            for (int k = 0; k < 4; ++k)
                if (eb + k < E) {
                    int s = srcE[eb + k], d = dstE[eb + k];
                    int bin = batch[d];
                    int old = atomicAdd(&lc[bin], 1);
                    pairs[lstart[bin] + old] = s | ((d - lns[bin]) << 17);
                }
        }
    }
}

__global__ __launch_bounds__(512) void k_csr_local(const int* __restrict__ pairs,
                                                   const int* __restrict__ boff,
                                                   const int* __restrict__ batch,
                                                   int E, int N, int G,
                                                   int* __restrict__ cnt, int* __restrict__ excl,
                                                   int* __restrict__ srcs) {
    __shared__ int lcnt[512];
    __shared__ int buf[512];
    __shared__ int lcur[512];
    int g = blockIdx.x, t = threadIdx.x;
    int lo = 0, hi = N;
    while (lo < hi) { int mid = (lo + hi) >> 1; if (batch[mid] < g) lo = mid + 1; else hi = mid; }
    int ns = lo;
    hi = N;
    while (lo < hi) { int mid = (lo + hi) >> 1; if (batch[mid] < g + 1) lo = mid + 1; else hi = mid; }
    int ne = lo;
    int lnodes = ne - ns;
    int es = boff[g];
    int ee = (g + 1 < G) ? boff[g + 1] : E;

    lcnt[t] = 0;
    __syncthreads();
    for (int e = es + t; e < ee; e += 512) atomicAdd(&lcnt[pairs[e] >> 17], 1);
    __syncthreads();
    int v = lcnt[t];
    buf[t] = v;
    __syncthreads();
    for (int off = 1; off < 512; off <<= 1) {
        int u = (t >= off) ? buf[t - off] : 0;
        __syncthreads();
        buf[t] += u;
        __syncthreads();
    }
    int lex = buf[t] - v;
    lcur[t] = lex;
    if (t < lnodes) {
        cnt[ns + t] = v;
        excl[ns + t] = es + lex;
    }
    __syncthreads();
    for (int e = es + t; e < ee; e += 512) {
        int pv = pairs[e];
        int pos = atomicAdd(&lcur[pv >> 17], 1);
        srcs[es + pos] = pv & 0x1FFFF;
    }
}

// ---------------- layer 1 gather + FUSED fin1 (fast ELU) ----------------
__global__ void k_gather1(const int* __restrict__ srcs, const int* __restrict__ excl,
                          const int* __restrict__ cnt,
                          const unsigned short* __restrict__ asrcb, const float* __restrict__ adst1,
                          const unsigned short* __restrict__ h1b,
                          const float* __restrict__ b1, const float* __restrict__ W2,
                          const float* __restrict__ a_src2, const float* __restrict__ a_dst2,
                          unsigned short* __restrict__ h2b, unsigned short* __restrict__ asrc2b,
                          float* __restrict__ adst2, int N) {
    int tid = blockIdx.x * 256 + threadIdx.x;
    int wave = tid >> 6;
    int lane = threadIdx.x & 63;
    int q = lane >> 3;            // node slot 0..7
    int l = lane & 7;             // head == channel group
    int wid = wave * 8 + q;
    if (wid >= N) return;
    int c0 = l * 8;               // channels c0..c0+7

    int beg = excl[wid];
    int cw  = cnt[wid];
    const int* sp = srcs + beg;
    float adh = adst1[wid * 8 + l];

    // self-loop init on chain 0
    uint4 us = *(const uint4*)&h1b[(size_t)wid * 64 + c0];
    float4 A0a, A0b;
    A0a.x = __uint_as_float(us.x << 16); A0a.y = __uint_as_float(us.x & 0xffff0000u);
    A0a.z = __uint_as_float(us.y << 16); A0a.w = __uint_as_float(us.y & 0xffff0000u);
    A0b.x = __uint_as_float(us.z << 16); A0b.y = __uint_as_float(us.z & 0xffff0000u);
    A0b.z = __uint_as_float(us.w << 16); A0b.w = __uint_as_float(us.w & 0xffff0000u);
    float m0 = LRELU(bf2f(asrcb[wid * 8 + l]) + adh), d0 = 1.f;
    float4 Z = {0.f, 0.f, 0.f, 0.f};
    float4 A1a = Z, A1b = Z, A2a = Z, A2b = Z, A3a = Z, A3b = Z;
    float m1 = -INFINITY, d1 = 0.f;
    float m2 = -INFINITY, d2 = 0.f;
    float m3 = -INFINITY, d3 = 0.f;

    int i = 0;
    for (; i + 4 <= cw; i += 4) {
        int s0 = sp[i], s1 = sp[i + 1], s2 = sp[i + 2], s3 = sp[i + 3];
        float e0 = LRELU(bf2f(asrcb[s0 * 8 + l]) + adh);
        float e1 = LRELU(bf2f(asrcb[s1 * 8 + l]) + adh);
        float e2 = LRELU(bf2f(asrcb[s2 * 8 + l]) + adh);
        float e3 = LRELU(bf2f(asrcb[s3 * 8 + l]) + adh);
        uint4 u0 = *(const uint4*)&h1b[(size_t)s0 * 64 + c0];
        uint4 u1 = *(const uint4*)&h1b[(size_t)s1 * 64 + c0];
        uint4 u2 = *(const uint4*)&h1b[(size_t)s2 * 64 + c0];
        uint4 u3 = *(const uint4*)&h1b[(size_t)s3 * 64 + c0];
        UPD8(m0, d0, A0a, A0b, e0, u0);
        UPD8(m1, d1, A1a, A1b, e1, u1);
        UPD8(m2, d2, A2a, A2b, e2, u2);
        UPD8(m3, d3, A3a, A3b, e3, u3);
    }
    for (; i < cw; ++i) {
        int s = sp[i];
        float ev = LRELU(bf2f(asrcb[s * 8 + l]) + adh);
        uint4 uv = *(const uint4*)&h1b[(size_t)s * 64 + c0];
        UPD8(m0, d0, A0a, A0b, ev, uv);
    }
    float mM = fmaxf(fmaxf(m0, m1), fmaxf(m2, m3));
    float w0 = fexp2(m0 - mM), w1 = fexp2(m1 - mM);
    float w2 = fexp2(m2 - mM), w3 = fexp2(m3 - mM);
    float den = d0 * w0 + d1 * w1 + d2 * w2 + d3 * w3;
    float inv = 1.f / (den + 1e-16f);
    float rv[8];
    rv[0] = (A0a.x * w0 + A1a.x * w1 + A2a.x * w2 + A3a.x * w3) * inv;
    rv[1] = (A0a.y * w0 + A1a.y * w1 + A2a.y * w2 + A3a.y * w3) * inv;
    rv[2] = (A0a.z * w0 + A1a.z * w1 + A2a.z * w2 + A3a.z * w3) * inv;
    rv[3] = (A0a.w * w0 + A1a.w * w1 + A2a.w * w2 + A3a.w * w3) * inv;
    rv[4] = (A0b.x * w0 + A1b.x * w1 + A2b.x * w2 + A3b.x * w3) * inv;
    rv[5] = (A0b.y * w0 + A1b.y * w1 + A2b.y * w2 + A3b.y * w3) * inv;
    rv[6] = (A0b.z * w0 + A1b.z * w1 + A2b.z * w2 + A3b.z * w3) * inv;
    rv[7] = (A0b.w * w0 + A1b.w * w1 + A2b.w * w2 + A3b.w * w3) * inv;

    // ---- fused fin1: felu(rv + b1) @ W2, 8-lane butterfly reduce ----
    float accj[10];
#pragma unroll
    for (int j = 0; j < 10; ++j) accj[j] = 0.f;
#pragma unroll
    for (int t = 0; t < 8; ++t) {
        float r = felu(rv[t] + b1[c0 + t]);
        const float* wr = W2 + (c0 + t) * 10;
#pragma unroll
        for (int j = 0; j < 10; ++j) accj[j] = fmaf(r, wr[j], accj[j]);
    }
#pragma unroll
    for (int mask = 1; mask <= 4; mask <<= 1)
#pragma unroll
        for (int j = 0; j < 10; ++j) accj[j] += __shfl_xor(accj[j], mask);

    if (l == 0) {
        float s = 0.f, d = 0.f;
        unsigned pw[5];
#pragma unroll
        for (int j = 0; j < 10; j += 2) {
            s = fmaf(accj[j], a_src2[j], s);     d = fmaf(accj[j], a_dst2[j], d);
            s = fmaf(accj[j+1], a_src2[j+1], s); d = fmaf(accj[j+1], a_dst2[j+1], d);
            pw[j >> 1] = (unsigned)f2bf(accj[j]) | ((unsigned)f2bf(accj[j+1]) << 16);
        }
        unsigned* hw = (unsigned*)&h2b[(size_t)wid * 10];
#pragma unroll
        for (int j = 0; j < 5; ++j) hw[j] = pw[j];
        asrc2b[wid] = f2bf(s * L2E);
        adst2[wid] = d * L2E;
    }
}

// ---------------- layer 2 gather: 4 nodes/wave, 16 lanes/node ----------------
__global__ void k_gather2(const int* __restrict__ srcs, const int* __restrict__ excl,
                          const int* __restrict__ cnt,
                          const unsigned short* __restrict__ asrc2b, const float* __restrict__ adst2,
                          const unsigned short* __restrict__ h2b, float* __restrict__ agg2, int N) {
    int tid = blockIdx.x * 256 + threadIdx.x;
    int wave = tid >> 6;
    int lane = threadIdx.x & 63;
    int q = lane >> 4;
    int l = lane & 15;
    int wid = wave * 4 + q;
    if (wid >= N) return;

    int beg = excl[wid];
    int cw  = cnt[wid];
    const int* sp = srcs + beg;
    float adn = adst2[wid];
    bool ld = l < 10;

    float m0 = LRELU(bf2f(asrc2b[wid]) + adn), d0 = 1.f;
    float a0 = ld ? bf2f(h2b[(size_t)wid * 10 + l]) : 0.f;
    float m1 = -INFINITY, d1 = 0.f, a1 = 0.f;
    float m2 = -INFINITY, d2 = 0.f, a2 = 0.f;
    float m3 = -INFINITY, d3 = 0.f, a3 = 0.f;

    int i = 0;
    for (; i + 4 <= cw; i += 4) {
        int s0 = sp[i], s1 = sp[i + 1], s2 = sp[i + 2], s3 = sp[i + 3];
        float e0 = LRELU(bf2f(asrc2b[s0]) + adn);
        float e1 = LRELU(bf2f(asrc2b[s1]) + adn);
        float e2 = LRELU(bf2f(asrc2b[s2]) + adn);
        float e3 = LRELU(bf2f(asrc2b[s3]) + adn);
        float g0 = ld ? bf2f(h2b[(size_t)s0 * 10 + l]) : 0.f;
        float g1 = ld ? bf2f(h2b[(size_t)s1 * 10 + l]) : 0.f;
        float g2 = ld ? bf2f(h2b[(size_t)s2 * 10 + l]) : 0.f;
        float g3 = ld ? bf2f(h2b[(size_t)s3 * 10 + l]) : 0.f;
        UPD1(m0, d0, a0, e0, g0);
        UPD1(m1, d1, a1, e1, g1);
        UPD1(m2, d2, a2, e2, g2);
        UPD1(m3, d3, a3, e3, g3);
    }
    for (; i < cw; ++i) {
        int s = sp[i];
        float ev = LRELU(bf2f(asrc2b[s]) + adn);
        float gv = ld ? bf2f(h2b[(size_t)s * 10 + l]) : 0.f;
        UPD1(m0, d0, a0, ev, gv);
    }
    float mM = fmaxf(fmaxf(m0, m1), fmaxf(m2, m3));
    float w0 = fexp2(m0 - mM), w1 = fexp2(m1 - mM);
    float w2 = fexp2(m2 - mM), w3 = fexp2(m3 - mM);
    float den = d0 * w0 + d1 * w1 + d2 * w2 + d3 * w3;
    float acc = a0 * w0 + a1 * w1 + a2 * w2 + a3 * w3;
    if (ld) agg2[(size_t)wid * 10 + l] = acc / (den + 1e-16f);
}

// ---------------- pool (+bias) + log_softmax; block per graph ----------------
__global__ void k_pool_final(const float* __restrict__ agg2, const float* __restrict__ b2,
                             const int* __restrict__ batch, float* __restrict__ out,
                             int N, int G) {
    int g = blockIdx.x;
    int lo = 0, hi = N;
    while (lo < hi) { int mid = (lo + hi) >> 1; if (batch[mid] < g) lo = mid + 1; else hi = mid; }
    int s = lo;
    lo = s; hi = N;
    while (lo < hi) { int mid = (lo + hi) >> 1; if (batch[mid] < g + 1) lo = mid + 1; else hi = mid; }
    int e = lo;
    int tid = threadIdx.x;
    float acc[10];
#pragma unroll
    for (int j = 0; j < 10; ++j) acc[j] = 0.f;
    for (int n = s + tid; n < e; n += 256) {
        const float* r = agg2 + (size_t)n * 10;
#pragma unroll
        for (int j = 0; j < 10; ++j) acc[j] += r[j];
    }
    __shared__ float red[256 * 10];
#pragma unroll
    for (int j = 0; j < 10; ++j) red[tid * 10 + j] = acc[j];
    __syncthreads();
    for (int st = 128; st > 0; st >>= 1) {
        if (tid < st)
#pragma unroll
            for (int j = 0; j < 10; ++j) red[tid * 10 + j] += red[(tid + st) * 10 + j];
        __syncthreads();
    }
    if (tid == 0) {
        int c = e - s;
        float v[10], m = -1e30f;
#pragma unroll
        for (int j = 0; j < 10; ++j) {
            v[j] = (c > 0) ? red[j] / (float)c + b2[j] : 0.f;
            m = fmaxf(m, v[j]);
        }
        float ssum = 0.f;
#pragma unroll
        for (int j = 0; j < 10; ++j) ssum += expf(v[j] - m);
        float ls = logf(ssum);
#pragma unroll
        for (int j = 0; j < 10; ++j) out[(size_t)g * 10 + j] = v[j] - m - ls;
    }
}

extern "C" void kernel_launch(void* const* d_in, const int* in_sizes, int n_in,
                              void* d_out, int out_size, void* d_ws, size_t ws_size,
                              hipStream_t stream) {
    const float* x     = (const float*)d_in[0];
    const int*   ei    = (const int*)d_in[1];
    const int*   batch = (const int*)d_in[2];
    const float* W1    = (const float*)d_in[3];
    const float* as1w  = (const float*)d_in[4];
    const float* ad1w  = (const float*)d_in[5];
    const float* b1    = (const float*)d_in[6];
    const float* W2    = (const float*)d_in[7];
    const float* as2w  = (const float*)d_in[8];
    const float* ad2w  = (const float*)d_in[9];
    const float* b2    = (const float*)d_in[10];

    const int N  = in_sizes[0] / 128;
    const int E  = in_sizes[1] / 2;
    const int G  = out_size / 10;
    const int* srcE = ei;
    const int* dstE = ei + E;

    auto cdiv = [](long long a, long long b) { return (int)((a + b - 1) / b); };
    const int NB = cdiv(E, CH);

    // ---- workspace layout ----
    size_t Nz = (size_t)N;
    unsigned short* h1b = (unsigned short*)d_ws;        // N*64 bf16
    float* agg2  = (float*)d_ws;                        // ALIAS: h1b dead after gather1
    unsigned short* asrc1b = h1b + Nz * 64;             // N*8 bf16
    float* adst1 = (float*)(asrc1b + Nz * 8);           // N*8 f32
    unsigned short* h2b = (unsigned short*)(adst1 + Nz * 8); // N*10 bf16
    unsigned short* asrc2b = h2b + Nz * 10;             // N bf16
    float* adst2 = (float*)(asrc2b + Nz + (Nz & 1));    // N f32 (align 4B)
    int* pairsA  = (int*)(adst2 + Nz);                  // E (packed src|ldst<<17)
    int* cntA    = pairsA + (size_t)E;                  // N
    int* exclA   = cntA + Nz;                           // N
    int* srcsA   = exclA + Nz;                          // E
    int* bhA     = srcsA + E;                           // 512*NB
    int* pstartA = bhA + (size_t)512 * NB;              // 512*NB
    int* totalA  = pstartA + (size_t)512 * NB;          // 512
    int* boffA   = totalA + 512;                        // 512
    int* nstartA = boffA + 512;                         // 512
    int* doneA   = nstartA + 512;                       // 1

    const int B = 256;

    // layer-1 MFMA GEMM with fused alpha dots
    int ntiles = cdiv(N, 16);
    int gB = ntiles < 2048 ? ntiles : 2048;
    k_gemm1_mfma<<<gB, B, 0, stream>>>(x, W1, as1w, ad1w, h1b, asrc1b, adst1, N, ntiles);

    // CSR build (scan_top folded into mscan via last-block pattern)
    k_bhist<<<NB, B, 0, stream>>>(dstE, batch, E, NB, G, bhA, doneA);
    k_mscan<<<512, 512, 0, stream>>>(bhA, NB, pstartA, totalA, boffA, nstartA, batch, N, G, doneA);
    k_bscatter<<<NB, B, 0, stream>>>(srcE, dstE, batch, boffA, pstartA, nstartA, E, NB, G, pairsA);
    k_csr_local<<<G, 512, 0, stream>>>(pairsA, boffA, batch, E, N, G, cntA, exclA, srcsA);

    // layer 1 gather + fused fin1: 32 nodes/block (8/wave), 8ch/lane
    k_gather1<<<cdiv(N, 32), B, 0, stream>>>(srcsA, exclA, cntA, asrc1b, adst1, h1b,
                                             b1, W2, as2w, ad2w, h2b, asrc2b, adst2, N);

    // layer 2 gather (agg2 aliases dead h1b)
    k_gather2<<<cdiv(N, 16), B, 0, stream>>>(srcsA, exclA, cntA, asrc2b, adst2, h2b, agg2, N);

    // pool + log_softmax
    k_pool_final<<<G, B, 0, stream>>>(agg2, b2, batch, (float*)d_out, N, G);
}

// Round 19
// 187.771 us; speedup vs baseline: 1.3341x; 1.3341x over previous
//
#include <hip/hip_runtime.h>
#include <math.h>

#define L2E 1.44269504088896f
#define LRELU(v) fmaxf((v), 0.2f * (v))

__device__ __forceinline__ float fexp2(float v) { return __builtin_amdgcn_exp2f(v); }
// fast ELU: exp(r)-1 via v_exp_f32 (vs ~30-inst libm expm1f)
__device__ __forceinline__ float felu(float r) {
    return r > 0.f ? r : fexp2(r * L2E) - 1.f;
}

// bf16 helpers (RNE pack, exact unpack)
__device__ __forceinline__ unsigned short f2bf(float f) {
    unsigned u = __float_as_uint(f);
    u += 0x7FFFu + ((u >> 16) & 1u);
    return (unsigned short)(u >> 16);
}
__device__ __forceinline__ float bf2f(unsigned short b) {
    return __uint_as_float((unsigned)b << 16);
}

typedef __attribute__((ext_vector_type(8))) short bf16x8;
typedef __attribute__((ext_vector_type(4))) float f32x4;

// base-2 online-softmax update, 8 channels packed in uint4 (bf16 pairs)
#define UPD8(mm, dd, Aa, Ab, ev, U)                                       \
    {                                                                     \
        float mn_ = fmaxf(mm, ev);                                        \
        float sc_ = fexp2(mm - mn_);                                      \
        float w_  = fexp2(ev - mn_);                                      \
        dd = dd * sc_ + w_;                                               \
        Aa.x = Aa.x * sc_ + w_ * __uint_as_float((U).x << 16);            \
        Aa.y = Aa.y * sc_ + w_ * __uint_as_float((U).x & 0xffff0000u);    \
        Aa.z = Aa.z * sc_ + w_ * __uint_as_float((U).y << 16);            \
        Aa.w = Aa.w * sc_ + w_ * __uint_as_float((U).y & 0xffff0000u);    \
        Ab.x = Ab.x * sc_ + w_ * __uint_as_float((U).z << 16);            \
        Ab.y = Ab.y * sc_ + w_ * __uint_as_float((U).z & 0xffff0000u);    \
        Ab.z = Ab.z * sc_ + w_ * __uint_as_float((U).w << 16);            \
        Ab.w = Ab.w * sc_ + w_ * __uint_as_float((U).w & 0xffff0000u);    \
        mm = mn_;                                                         \
    }
#define UPD1(mm, dd, aa, ev, hv)           \
    {                                      \
        float mn_ = fmaxf(mm, ev);         \
        float sc_ = fexp2(mm - mn_);       \
        float w_  = fexp2(ev - mn_);       \
        dd = dd * sc_ + w_;                \
        aa = aa * sc_ + w_ * (hv);         \
        mm = mn_;                          \
    }

#define CH 4096   // edges per histogram/scatter block

// ---------------- layer-1 GEMM via MFMA + FUSED alpha dots ----------------
__global__ __launch_bounds__(256) void k_gemm1_mfma(
        const float* __restrict__ x, const float* __restrict__ W,
        const float* __restrict__ a_src, const float* __restrict__ a_dst,
        unsigned short* __restrict__ h1b, unsigned short* __restrict__ asrcb,
        float* __restrict__ adst1, int N, int ntiles) {
    int tid = threadIdx.x;
    int w = tid >> 6, l = tid & 63;
    int c0 = w * 16;
    int lr = l & 15;
    int lg = l >> 4;

    bf16x8 bfr[4];
#pragma unroll
    for (int kk = 0; kk < 4; ++kk)
#pragma unroll
        for (int j = 0; j < 8; ++j)
            bfr[kk][j] = (short)f2bf(W[(size_t)(kk * 32 + lg * 8 + j) * 64 + c0 + lr]);

    float asv = a_src[c0 + lr];   // per-lane alpha weights (col c0+lr)
    float adv = a_dst[c0 + lr];

    for (int t = blockIdx.x; t < ntiles; t += gridDim.x) {
        int n0 = t * 16;
        int n = n0 + lr;
        const float4* xr = (const float4*)(x + (size_t)(n < N ? n : 0) * 128);
        f32x4 acc = {0.f, 0.f, 0.f, 0.f};
#pragma unroll
        for (int kk = 0; kk < 4; ++kk) {
            float4 u0 = xr[kk * 8 + lg * 2];
            float4 u1 = xr[kk * 8 + lg * 2 + 1];
            bf16x8 afr;
            afr[0] = (short)f2bf(u0.x); afr[1] = (short)f2bf(u0.y);
            afr[2] = (short)f2bf(u0.z); afr[3] = (short)f2bf(u0.w);
            afr[4] = (short)f2bf(u1.x); afr[5] = (short)f2bf(u1.y);
            afr[6] = (short)f2bf(u1.z); afr[7] = (short)f2bf(u1.w);
            acc = __builtin_amdgcn_mfma_f32_16x16x32_bf16(afr, bfr[kk], acc, 0, 0, 0);
        }
        // h1 store
#pragma unroll
        for (int r = 0; r < 4; ++r) {
            int nn = n0 + lg * 4 + r;
            if (nn < N) h1b[(size_t)nn * 64 + c0 + lr] = f2bf(acc[r]);
        }
        // fused alpha dots: partials then 8-lane butterfly
        float ps[4], pd[4];
#pragma unroll
        for (int r = 0; r < 4; ++r) { ps[r] = acc[r] * asv; pd[r] = acc[r] * adv; }
#pragma unroll
        for (int mask = 1; mask <= 4; mask <<= 1)
#pragma unroll
            for (int r = 0; r < 4; ++r) {
                ps[r] += __shfl_xor(ps[r], mask);
                pd[r] += __shfl_xor(pd[r], mask);
            }
        if ((lr & 7) == 0) {
            int h = (c0 + lr) >> 3;   // 2w or 2w+1
#pragma unroll
            for (int r = 0; r < 4; ++r) {
                int nn = n0 + lg * 4 + r;
                if (nn < N) {
                    asrcb[nn * 8 + h] = f2bf(ps[r] * L2E);
                    adst1[nn * 8 + h] = pd[r] * L2E;
                }
            }
        }
    }
}

// ---------------- graph-bucket sort (zero global atomics, 4-way ILP) ----------------

__global__ __launch_bounds__(256) void k_bhist(const int* __restrict__ dstE,
                                               const int* __restrict__ batch,
                                               int E, int NB, int G, int* __restrict__ bh) {
    __shared__ int lh[512];
    int tid = threadIdx.x, b = blockIdx.x;
    lh[tid] = 0; lh[tid + 256] = 0;
    __syncthreads();
#pragma unroll
    for (int i = 0; i < CH / 1024; ++i) {
        int eb = b * CH + (i * 256 + tid) * 4;
        if (eb + 3 < E) {
            int4 dv = *(const int4*)(dstE + eb);
            int g0 = batch[dv.x], g1 = batch[dv.y], g2 = batch[dv.z], g3 = batch[dv.w];
            atomicAdd(&lh[g0], 1); atomicAdd(&lh[g1], 1);
            atomicAdd(&lh[g2], 1); atomicAdd(&lh[g3], 1);
        } else {
#pragma unroll
            for (int k = 0; k < 4; ++k)
                if (eb + k < E) atomicAdd(&lh[batch[dstE[eb + k]]], 1);
        }
    }
    __syncthreads();
    if (tid < G)       bh[(size_t)tid * NB + b] = lh[tid];
    if (tid + 256 < G) bh[(size_t)(tid + 256) * NB + b] = lh[tid + 256];
}

__global__ __launch_bounds__(512) void k_mscan(const int* __restrict__ bh, int NB,
                                               int* __restrict__ pstart, int* __restrict__ total) {
    __shared__ int buf[512];
    int bin = blockIdx.x, t = threadIdx.x;
    int v = (t < NB) ? bh[(size_t)bin * NB + t] : 0;
    buf[t] = v;
    __syncthreads();
    for (int off = 1; off < 512; off <<= 1) {
        int u = (t >= off) ? buf[t - off] : 0;
        __syncthreads();
        buf[t] += u;
        __syncthreads();
    }
    if (t < NB) pstart[(size_t)bin * NB + t] = buf[t] - v;
    if (t == 511) total[bin] = buf[511];
}

// exclusive scan of totals -> boff; also nstart[g] = lower_bound(batch, g)
__global__ __launch_bounds__(1024) void k_scan_top(const int* __restrict__ total, int nb,
                                                   int* __restrict__ boff,
                                                   const int* __restrict__ batch, int N,
                                                   int* __restrict__ nstart) {
    __shared__ int buf[1024];
    int t = threadIdx.x;
    int v = (t < nb) ? total[t] : 0;
    buf[t] = v;
    __syncthreads();
    for (int off = 1; off < 1024; off <<= 1) {
        int u = (t >= off) ? buf[t - off] : 0;
        __syncthreads();
        buf[t] += u;
        __syncthreads();
    }
    if (t < nb) {
        boff[t] = buf[t] - v;
        int lo = 0, hi = N;
        while (lo < hi) { int mid = (lo + hi) >> 1; if (batch[mid] < t) lo = mid + 1; else hi = mid; }
        nstart[t] = lo;
    }
}

// scatter edges into graph buckets as packed int: src | (local_dst << 17)
__global__ __launch_bounds__(256) void k_bscatter(const int* __restrict__ srcE,
                                                  const int* __restrict__ dstE,
                                                  const int* __restrict__ batch,
                                                  const int* __restrict__ boff,
                                                  const int* __restrict__ pstart,
                                                  const int* __restrict__ nstart,
                                                  int E, int NB, int G, int* __restrict__ pairs) {
    __shared__ int lstart[512];
    __shared__ int lc[512];
    __shared__ int lns[512];
    int tid = threadIdx.x, b = blockIdx.x;
#pragma unroll
    for (int j = tid; j < 512; j += 256) {
        lstart[j] = (j < G) ? boff[j] + pstart[(size_t)j * NB + b] : 0;
        lns[j] = (j < G) ? nstart[j] : 0;
        lc[j] = 0;
    }
    __syncthreads();
#pragma unroll
    for (int i = 0; i < CH / 1024; ++i) {
        int eb = b * CH + (i * 256 + tid) * 4;
        if (eb + 3 < E) {
            int4 sv = *(const int4*)(srcE + eb);
            int4 dv = *(const int4*)(dstE + eb);
            int g0 = batch[dv.x], g1 = batch[dv.y], g2 = batch[dv.z], g3 = batch[dv.w];
            int p0 = atomicAdd(&lc[g0], 1);
            int p1 = atomicAdd(&lc[g1], 1);
            int p2 = atomicAdd(&lc[g2], 1);
            int p3 = atomicAdd(&lc[g3], 1);
            pairs[lstart[g0] + p0] = sv.x | ((dv.x - lns[g0]) << 17);
            pairs[lstart[g1] + p1] = sv.y | ((dv.y - lns[g1]) << 17);
            pairs[lstart[g2] + p2] = sv.z | ((dv.z - lns[g2]) << 17);
            pairs[lstart[g3] + p3] = sv.w | ((dv.w - lns[g3]) << 17);
        } else {
#pragma unroll
            for (int k = 0; k < 4; ++k)
                if (eb + k < E) {
                    int s = srcE[eb + k], d = dstE[eb + k];
                    int bin = batch[d];
                    int old = atomicAdd(&lc[bin], 1);
                    pairs[lstart[bin] + old] = s | ((d - lns[bin]) << 17);
                }
        }
    }
}

__global__ __launch_bounds__(512) void k_csr_local(const int* __restrict__ pairs,
                                                   const int* __restrict__ boff,
                                                   const int* __restrict__ batch,
                                                   int E, int N, int G,
                                                   int* __restrict__ cnt, int* __restrict__ excl,
                                                   int* __restrict__ srcs) {
    __shared__ int lcnt[512];
    __shared__ int buf[512];
    __shared__ int lcur[512];
    int g = blockIdx.x, t = threadIdx.x;
    int lo = 0, hi = N;
    while (lo < hi) { int mid = (lo + hi) >> 1; if (batch[mid] < g) lo = mid + 1; else hi = mid; }
    int ns = lo;
    hi = N;
    while (lo < hi) { int mid = (lo + hi) >> 1; if (batch[mid] < g + 1) lo = mid + 1; else hi = mid; }
    int ne = lo;
    int lnodes = ne - ns;
    int es = boff[g];
    int ee = (g + 1 < G) ? boff[g + 1] : E;

    lcnt[t] = 0;
    __syncthreads();
    for (int e = es + t; e < ee; e += 512) atomicAdd(&lcnt[pairs[e] >> 17], 1);
    __syncthreads();
    int v = lcnt[t];
    buf[t] = v;
    __syncthreads();
    for (int off = 1; off < 512; off <<= 1) {
        int u = (t >= off) ? buf[t - off] : 0;
        __syncthreads();
        buf[t] += u;
        __syncthreads();
    }
    int lex = buf[t] - v;
    lcur[t] = lex;
    if (t < lnodes) {
        cnt[ns + t] = v;
        excl[ns + t] = es + lex;
    }
    __syncthreads();
    for (int e = es + t; e < ee; e += 512) {
        int pv = pairs[e];
        int pos = atomicAdd(&lcur[pv >> 17], 1);
        srcs[es + pos] = pv & 0x1FFFF;
    }
}

// ---------------- layer 1 gather + FUSED fin1 (fast ELU) ----------------
__global__ void k_gather1(const int* __restrict__ srcs, const int* __restrict__ excl,
                          const int* __restrict__ cnt,
                          const unsigned short* __restrict__ asrcb, const float* __restrict__ adst1,
                          const unsigned short* __restrict__ h1b,
                          const float* __restrict__ b1, const float* __restrict__ W2,
                          const float* __restrict__ a_src2, const float* __restrict__ a_dst2,
                          unsigned short* __restrict__ h2b, unsigned short* __restrict__ asrc2b,
                          float* __restrict__ adst2, int N) {
    int tid = blockIdx.x * 256 + threadIdx.x;
    int wave = tid >> 6;
    int lane = threadIdx.x & 63;
    int q = lane >> 3;            // node slot 0..7
    int l = lane & 7;             // head == channel group
    int wid = wave * 8 + q;
    if (wid >= N) return;
    int c0 = l * 8;               // channels c0..c0+7

    int beg = excl[wid];
    int cw  = cnt[wid];
    const int* sp = srcs + beg;
    float adh = adst1[wid * 8 + l];

    // self-loop init on chain 0
    uint4 us = *(const uint4*)&h1b[(size_t)wid * 64 + c0];
    float4 A0a, A0b;
    A0a.x = __uint_as_float(us.x << 16); A0a.y = __uint_as_float(us.x & 0xffff0000u);
    A0a.z = __uint_as_float(us.y << 16); A0a.w = __uint_as_float(us.y & 0xffff0000u);
    A0b.x = __uint_as_float(us.z << 16); A0b.y = __uint_as_float(us.z & 0xffff0000u);
    A0b.z = __uint_as_float(us.w << 16); A0b.w = __uint_as_float(us.w & 0xffff0000u);
    float m0 = LRELU(bf2f(asrcb[wid * 8 + l]) + adh), d0 = 1.f;
    float4 Z = {0.f, 0.f, 0.f, 0.f};
    float4 A1a = Z, A1b = Z, A2a = Z, A2b = Z, A3a = Z, A3b = Z;
    float m1 = -INFINITY, d1 = 0.f;
    float m2 = -INFINITY, d2 = 0.f;
    float m3 = -INFINITY, d3 = 0.f;

    int i = 0;
    for (; i + 4 <= cw; i += 4) {
        int s0 = sp[i], s1 = sp[i + 1], s2 = sp[i + 2], s3 = sp[i + 3];
        float e0 = LRELU(bf2f(asrcb[s0 * 8 + l]) + adh);
        float e1 = LRELU(bf2f(asrcb[s1 * 8 + l]) + adh);
        float e2 = LRELU(bf2f(asrcb[s2 * 8 + l]) + adh);
        float e3 = LRELU(bf2f(asrcb[s3 * 8 + l]) + adh);
        uint4 u0 = *(const uint4*)&h1b[(size_t)s0 * 64 + c0];
        uint4 u1 = *(const uint4*)&h1b[(size_t)s1 * 64 + c0];
        uint4 u2 = *(const uint4*)&h1b[(size_t)s2 * 64 + c0];
        uint4 u3 = *(const uint4*)&h1b[(size_t)s3 * 64 + c0];
        UPD8(m0, d0, A0a, A0b, e0, u0);
        UPD8(m1, d1, A1a, A1b, e1, u1);
        UPD8(m2, d2, A2a, A2b, e2, u2);
        UPD8(m3, d3, A3a, A3b, e3, u3);
    }
    for (; i < cw; ++i) {
        int s = sp[i];
        float ev = LRELU(bf2f(asrcb[s * 8 + l]) + adh);
        uint4 uv = *(const uint4*)&h1b[(size_t)s * 64 + c0];
        UPD8(m0, d0, A0a, A0b, ev, uv);
    }
    float mM = fmaxf(fmaxf(m0, m1), fmaxf(m2, m3));
    float w0 = fexp2(m0 - mM), w1 = fexp2(m1 - mM);
    float w2 = fexp2(m2 - mM), w3 = fexp2(m3 - mM);
    float den = d0 * w0 + d1 * w1 + d2 * w2 + d3 * w3;
    float inv = 1.f / (den + 1e-16f);
    float rv[8];
    rv[0] = (A0a.x * w0 + A1a.x * w1 + A2a.x * w2 + A3a.x * w3) * inv;
    rv[1] = (A0a.y * w0 + A1a.y * w1 + A2a.y * w2 + A3a.y * w3) * inv;
    rv[2] = (A0a.z * w0 + A1a.z * w1 + A2a.z * w2 + A3a.z * w3) * inv;
    rv[3] = (A0a.w * w0 + A1a.w * w1 + A2a.w * w2 + A3a.w * w3) * inv;
    rv[4] = (A0b.x * w0 + A1b.x * w1 + A2b.x * w2 + A3b.x * w3) * inv;
    rv[5] = (A0b.y * w0 + A1b.y * w1 + A2b.y * w2 + A3b.y * w3) * inv;
    rv[6] = (A0b.z * w0 + A1b.z * w1 + A2b.z * w2 + A3b.z * w3) * inv;
    rv[7] = (A0b.w * w0 + A1b.w * w1 + A2b.w * w2 + A3b.w * w3) * inv;

    // ---- fused fin1: felu(rv + b1) @ W2, 8-lane butterfly reduce ----
    float accj[10];
#pragma unroll
    for (int j = 0; j < 10; ++j) accj[j] = 0.f;
#pragma unroll
    for (int t = 0; t < 8; ++t) {
        float r = felu(rv[t] + b1[c0 + t]);
        const float* wr = W2 + (c0 + t) * 10;
#pragma unroll
        for (int j = 0; j < 10; ++j) accj[j] = fmaf(r, wr[j], accj[j]);
    }
#pragma unroll
    for (int mask = 1; mask <= 4; mask <<= 1)
#pragma unroll
        for (int j = 0; j < 10; ++j) accj[j] += __shfl_xor(accj[j], mask);

    if (l == 0) {
        float s = 0.f, d = 0.f;
        unsigned pw[5];
#pragma unroll
        for (int j = 0; j < 10; j += 2) {
            s = fmaf(accj[j], a_src2[j], s);     d = fmaf(accj[j], a_dst2[j], d);
            s = fmaf(accj[j+1], a_src2[j+1], s); d = fmaf(accj[j+1], a_dst2[j+1], d);
            pw[j >> 1] = (unsigned)f2bf(accj[j]) | ((unsigned)f2bf(accj[j+1]) << 16);
        }
        unsigned* hw = (unsigned*)&h2b[(size_t)wid * 10];
#pragma unroll
        for (int j = 0; j < 5; ++j) hw[j] = pw[j];
        asrc2b[wid] = f2bf(s * L2E);
        adst2[wid] = d * L2E;
    }
}

// ---------------- layer 2 gather: 4 nodes/wave, 16 lanes/node ----------------
__global__ void k_gather2(const int* __restrict__ srcs, const int* __restrict__ excl,
                          const int* __restrict__ cnt,
                          const unsigned short* __restrict__ asrc2b, const float* __restrict__ adst2,
                          const unsigned short* __restrict__ h2b, float* __restrict__ agg2, int N) {
    int tid = blockIdx.x * 256 + threadIdx.x;
    int wave = tid >> 6;
    int lane = threadIdx.x & 63;
    int q = lane >> 4;
    int l = lane & 15;
    int wid = wave * 4 + q;
    if (wid >= N) return;

    int beg = excl[wid];
    int cw  = cnt[wid];
    const int* sp = srcs + beg;
    float adn = adst2[wid];
    bool ld = l < 10;

    float m0 = LRELU(bf2f(asrc2b[wid]) + adn), d0 = 1.f;
    float a0 = ld ? bf2f(h2b[(size_t)wid * 10 + l]) : 0.f;
    float m1 = -INFINITY, d1 = 0.f, a1 = 0.f;
    float m2 = -INFINITY, d2 = 0.f, a2 = 0.f;
    float m3 = -INFINITY, d3 = 0.f, a3 = 0.f;

    int i = 0;
    for (; i + 4 <= cw; i += 4) {
        int s0 = sp[i], s1 = sp[i + 1], s2 = sp[i + 2], s3 = sp[i + 3];
        float e0 = LRELU(bf2f(asrc2b[s0]) + adn);
        float e1 = LRELU(bf2f(asrc2b[s1]) + adn);
        float e2 = LRELU(bf2f(asrc2b[s2]) + adn);
        float e3 = LRELU(bf2f(asrc2b[s3]) + adn);
        float g0 = ld ? bf2f(h2b[(size_t)s0 * 10 + l]) : 0.f;
        float g1 = ld ? bf2f(h2b[(size_t)s1 * 10 + l]) : 0.f;
        float g2 = ld ? bf2f(h2b[(size_t)s2 * 10 + l]) : 0.f;
        float g3 = ld ? bf2f(h2b[(size_t)s3 * 10 + l]) : 0.f;
        UPD1(m0, d0, a0, e0, g0);
        UPD1(m1, d1, a1, e1, g1);
        UPD1(m2, d2, a2, e2, g2);
        UPD1(m3, d3, a3, e3, g3);
    }
    for (; i < cw; ++i) {
        int s = sp[i];
        float ev = LRELU(bf2f(asrc2b[s]) + adn);
        float gv = ld ? bf2f(h2b[(size_t)s * 10 + l]) : 0.f;
        UPD1(m0, d0, a0, ev, gv);
    }
    float mM = fmaxf(fmaxf(m0, m1), fmaxf(m2, m3));
    float w0 = fexp2(m0 - mM), w1 = fexp2(m1 - mM);
    float w2 = fexp2(m2 - mM), w3 = fexp2(m3 - mM);
    float den = d0 * w0 + d1 * w1 + d2 * w2 + d3 * w3;
    float acc = a0 * w0 + a1 * w1 + a2 * w2 + a3 * w3;
    if (ld) agg2[(size_t)wid * 10 + l] = acc / (den + 1e-16f);
}

// ---------------- pool (+bias) + log_softmax; block per graph ----------------
__global__ void k_pool_final(const float* __restrict__ agg2, const float* __restrict__ b2,
                             const int* __restrict__ batch, float* __restrict__ out,
                             int N, int G) {
    int g = blockIdx.x;
    int lo = 0, hi = N;
    while (lo < hi) { int mid = (lo + hi) >> 1; if (batch[mid] < g) lo = mid + 1; else hi = mid; }
    int s = lo;
    lo = s; hi = N;
    while (lo < hi) { int mid = (lo + hi) >> 1; if (batch[mid] < g + 1) lo = mid + 1; else hi = mid; }
    int e = lo;
    int tid = threadIdx.x;
    float acc[10];
#pragma unroll
    for (int j = 0; j < 10; ++j) acc[j] = 0.f;
    for (int n = s + tid; n < e; n += 256) {
        const float* r = agg2 + (size_t)n * 10;
#pragma unroll
        for (int j = 0; j < 10; ++j) acc[j] += r[j];
    }
    __shared__ float red[256 * 10];
#pragma unroll
    for (int j = 0; j < 10; ++j) red[tid * 10 + j] = acc[j];
    __syncthreads();
    for (int st = 128; st > 0; st >>= 1) {
        if (tid < st)
#pragma unroll
            for (int j = 0; j < 10; ++j) red[tid * 10 + j] += red[(tid + st) * 10 + j];
        __syncthreads();
    }
    if (tid == 0) {
        int c = e - s;
        float v[10], m = -1e30f;
#pragma unroll
        for (int j = 0; j < 10; ++j) {
            v[j] = (c > 0) ? red[j] / (float)c + b2[j] : 0.f;
            m = fmaxf(m, v[j]);
        }
        float ssum = 0.f;
#pragma unroll
        for (int j = 0; j < 10; ++j) ssum += expf(v[j] - m);
        float ls = logf(ssum);
#pragma unroll
        for (int j = 0; j < 10; ++j) out[(size_t)g * 10 + j] = v[j] - m - ls;
    }
}

extern "C" void kernel_launch(void* const* d_in, const int* in_sizes, int n_in,
                              void* d_out, int out_size, void* d_ws, size_t ws_size,
                              hipStream_t stream) {
    const float* x     = (const float*)d_in[0];
    const int*   ei    = (const int*)d_in[1];
    const int*   batch = (const int*)d_in[2];
    const float* W1    = (const float*)d_in[3];
    const float* as1w  = (const float*)d_in[4];
    const float* ad1w  = (const float*)d_in[5];
    const float* b1    = (const float*)d_in[6];
    const float* W2    = (const float*)d_in[7];
    const float* as2w  = (const float*)d_in[8];
    const float* ad2w  = (const float*)d_in[9];
    const float* b2    = (const float*)d_in[10];

    const int N  = in_sizes[0] / 128;
    const int E  = in_sizes[1] / 2;
    const int G  = out_size / 10;
    const int* srcE = ei;
    const int* dstE = ei + E;

    auto cdiv = [](long long a, long long b) { return (int)((a + b - 1) / b); };
    const int NB = cdiv(E, CH);

    // ---- workspace layout ----
    size_t Nz = (size_t)N;
    unsigned short* h1b = (unsigned short*)d_ws;        // N*64 bf16
    float* agg2  = (float*)d_ws;                        // ALIAS: h1b dead after gather1
    unsigned short* asrc1b = h1b + Nz * 64;             // N*8 bf16
    float* adst1 = (float*)(asrc1b + Nz * 8);           // N*8 f32
    unsigned short* h2b = (unsigned short*)(adst1 + Nz * 8); // N*10 bf16
    unsigned short* asrc2b = h2b + Nz * 10;             // N bf16
    float* adst2 = (float*)(asrc2b + Nz + (Nz & 1));    // N f32 (align 4B)
    int* pairsA  = (int*)(adst2 + Nz);                  // E (packed src|ldst<<17)
    int* cntA    = pairsA + (size_t)E;                  // N
    int* exclA   = cntA + Nz;                           // N
    int* srcsA   = exclA + Nz;                          // E
    int* bhA     = srcsA + E;                           // 512*NB
    int* pstartA = bhA + (size_t)512 * NB;              // 512*NB
    int* totalA  = pstartA + (size_t)512 * NB;          // 512
    int* boffA   = totalA + 512;                        // 512
    int* nstartA = boffA + 512;                         // 512

    const int B = 256;

    // layer-1 MFMA GEMM with fused alpha dots
    int ntiles = cdiv(N, 16);
    int gB = ntiles < 2048 ? ntiles : 2048;
    k_gemm1_mfma<<<gB, B, 0, stream>>>(x, W1, as1w, ad1w, h1b, asrc1b, adst1, N, ntiles);

    // CSR build (two-kernel scan: no device-scope fences)
    k_bhist<<<NB, B, 0, stream>>>(dstE, batch, E, NB, G, bhA);
    k_mscan<<<512, 512, 0, stream>>>(bhA, NB, pstartA, totalA);
    k_scan_top<<<1, 1024, 0, stream>>>(totalA, G, boffA, batch, N, nstartA);
    k_bscatter<<<NB, B, 0, stream>>>(srcE, dstE, batch, boffA, pstartA, nstartA, E, NB, G, pairsA);
    k_csr_local<<<G, 512, 0, stream>>>(pairsA, boffA, batch, E, N, G, cntA, exclA, srcsA);

    // layer 1 gather + fused fin1: 32 nodes/block (8/wave), 8ch/lane
    k_gather1<<<cdiv(N, 32), B, 0, stream>>>(srcsA, exclA, cntA, asrc1b, adst1, h1b,
                                             b1, W2, as2w, ad2w, h2b, asrc2b, adst2, N);

    // layer 2 gather (agg2 aliases dead h1b)
    k_gather2<<<cdiv(N, 16), B, 0, stream>>>(srcsA, exclA, cntA, asrc2b, adst2, h2b, agg2, N);

    // pool + log_softmax
    k_pool_final<<<G, B, 0, stream>>>(agg2, b2, batch, (float*)d_out, N, G);
}

// Round 20
// 184.824 us; speedup vs baseline: 1.3554x; 1.0159x over previous
//
#include <hip/hip_runtime.h>
#include <math.h>

#define L2E 1.44269504088896f
#define LRELU(v) fmaxf((v), 0.2f * (v))

__device__ __forceinline__ float fexp2(float v) { return __builtin_amdgcn_exp2f(v); }
// fast ELU: exp(r)-1 via v_exp_f32 (vs ~30-inst libm expm1f)
__device__ __forceinline__ float felu(float r) {
    return r > 0.f ? r : fexp2(r * L2E) - 1.f;
}

// bf16 helpers (RNE pack, exact unpack)
__device__ __forceinline__ unsigned short f2bf(float f) {
    unsigned u = __float_as_uint(f);
    u += 0x7FFFu + ((u >> 16) & 1u);
    return (unsigned short)(u >> 16);
}
__device__ __forceinline__ float bf2f(unsigned short b) {
    return __uint_as_float((unsigned)b << 16);
}

typedef __attribute__((ext_vector_type(8))) short bf16x8;
typedef __attribute__((ext_vector_type(4))) float f32x4;

// base-2 online-softmax update, 8 channels packed in uint4 (bf16 pairs)
#define UPD8(mm, dd, Aa, Ab, ev, U)                                       \
    {                                                                     \
        float mn_ = fmaxf(mm, ev);                                        \
        float sc_ = fexp2(mm - mn_);                                      \
        float w_  = fexp2(ev - mn_);                                      \
        dd = dd * sc_ + w_;                                               \
        Aa.x = Aa.x * sc_ + w_ * __uint_as_float((U).x << 16);            \
        Aa.y = Aa.y * sc_ + w_ * __uint_as_float((U).x & 0xffff0000u);    \
        Aa.z = Aa.z * sc_ + w_ * __uint_as_float((U).y << 16);            \
        Aa.w = Aa.w * sc_ + w_ * __uint_as_float((U).y & 0xffff0000u);    \
        Ab.x = Ab.x * sc_ + w_ * __uint_as_float((U).z << 16);            \
        Ab.y = Ab.y * sc_ + w_ * __uint_as_float((U).z & 0xffff0000u);    \
        Ab.z = Ab.z * sc_ + w_ * __uint_as_float((U).w << 16);            \
        Ab.w = Ab.w * sc_ + w_ * __uint_as_float((U).w & 0xffff0000u);    \
        mm = mn_;                                                         \
    }
#define UPD1(mm, dd, aa, ev, hv)           \
    {                                      \
        float mn_ = fmaxf(mm, ev);         \
        float sc_ = fexp2(mm - mn_);       \
        float w_  = fexp2(ev - mn_);       \
        dd = dd * sc_ + w_;                \
        aa = aa * sc_ + w_ * (hv);         \
        mm = mn_;                          \
    }

#define CH 4096   // edges per histogram/scatter block

// ---------------- layer-1 GEMM via MFMA + FUSED alpha dots ----------------
__global__ __launch_bounds__(256) void k_gemm1_mfma(
        const float* __restrict__ x, const float* __restrict__ W,
        const float* __restrict__ a_src, const float* __restrict__ a_dst,
        unsigned short* __restrict__ h1b, unsigned short* __restrict__ asrcb,
        float* __restrict__ adst1, int N, int ntiles) {
    int tid = threadIdx.x;
    int w = tid >> 6, l = tid & 63;
    int c0 = w * 16;
    int lr = l & 15;
    int lg = l >> 4;

    bf16x8 bfr[4];
#pragma unroll
    for (int kk = 0; kk < 4; ++kk)
#pragma unroll
        for (int j = 0; j < 8; ++j)
            bfr[kk][j] = (short)f2bf(W[(size_t)(kk * 32 + lg * 8 + j) * 64 + c0 + lr]);

    float asv = a_src[c0 + lr];   // per-lane alpha weights (col c0+lr)
    float adv = a_dst[c0 + lr];

    for (int t = blockIdx.x; t < ntiles; t += gridDim.x) {
        int n0 = t * 16;
        int n = n0 + lr;
        const float4* xr = (const float4*)(x + (size_t)(n < N ? n : 0) * 128);
        f32x4 acc = {0.f, 0.f, 0.f, 0.f};
#pragma unroll
        for (int kk = 0; kk < 4; ++kk) {
            float4 u0 = xr[kk * 8 + lg * 2];
            float4 u1 = xr[kk * 8 + lg * 2 + 1];
            bf16x8 afr;
            afr[0] = (short)f2bf(u0.x); afr[1] = (short)f2bf(u0.y);
            afr[2] = (short)f2bf(u0.z); afr[3] = (short)f2bf(u0.w);
            afr[4] = (short)f2bf(u1.x); afr[5] = (short)f2bf(u1.y);
            afr[6] = (short)f2bf(u1.z); afr[7] = (short)f2bf(u1.w);
            acc = __builtin_amdgcn_mfma_f32_16x16x32_bf16(afr, bfr[kk], acc, 0, 0, 0);
        }
        // h1 store
#pragma unroll
        for (int r = 0; r < 4; ++r) {
            int nn = n0 + lg * 4 + r;
            if (nn < N) h1b[(size_t)nn * 64 + c0 + lr] = f2bf(acc[r]);
        }
        // fused alpha dots: partials then 8-lane butterfly
        float ps[4], pd[4];
#pragma unroll
        for (int r = 0; r < 4; ++r) { ps[r] = acc[r] * asv; pd[r] = acc[r] * adv; }
#pragma unroll
        for (int mask = 1; mask <= 4; mask <<= 1)
#pragma unroll
            for (int r = 0; r < 4; ++r) {
                ps[r] += __shfl_xor(ps[r], mask);
                pd[r] += __shfl_xor(pd[r], mask);
            }
        if ((lr & 7) == 0) {
            int h = (c0 + lr) >> 3;   // 2w or 2w+1
#pragma unroll
            for (int r = 0; r < 4; ++r) {
                int nn = n0 + lg * 4 + r;
                if (nn < N) {
                    asrcb[nn * 8 + h] = f2bf(ps[r] * L2E);
                    adst1[nn * 8 + h] = pd[r] * L2E;
                }
            }
        }
    }
}

// ---------------- graph-bucket sort (zero global atomics, 4-way ILP) ----------------

__global__ __launch_bounds__(256) void k_bhist(const int* __restrict__ dstE,
                                               const int* __restrict__ batch,
                                               int E, int NB, int G, int* __restrict__ bh) {
    __shared__ int lh[512];
    int tid = threadIdx.x, b = blockIdx.x;
    lh[tid] = 0; lh[tid + 256] = 0;
    __syncthreads();
#pragma unroll
    for (int i = 0; i < CH / 1024; ++i) {
        int eb = b * CH + (i * 256 + tid) * 4;
        if (eb + 3 < E) {
            int4 dv = *(const int4*)(dstE + eb);
            int g0 = batch[dv.x], g1 = batch[dv.y], g2 = batch[dv.z], g3 = batch[dv.w];
            atomicAdd(&lh[g0], 1); atomicAdd(&lh[g1], 1);
            atomicAdd(&lh[g2], 1); atomicAdd(&lh[g3], 1);
        } else {
#pragma unroll
            for (int k = 0; k < 4; ++k)
                if (eb + k < E) atomicAdd(&lh[batch[dstE[eb + k]]], 1);
        }
    }
    __syncthreads();
    if (tid < G)       bh[(size_t)tid * NB + b] = lh[tid];
    if (tid + 256 < G) bh[(size_t)(tid + 256) * NB + b] = lh[tid + 256];
}

__global__ __launch_bounds__(512) void k_mscan(const int* __restrict__ bh, int NB,
                                               int* __restrict__ pstart, int* __restrict__ total) {
    __shared__ int buf[512];
    int bin = blockIdx.x, t = threadIdx.x;
    int v = (t < NB) ? bh[(size_t)bin * NB + t] : 0;
    buf[t] = v;
    __syncthreads();
    for (int off = 1; off < 512; off <<= 1) {
        int u = (t >= off) ? buf[t - off] : 0;
        __syncthreads();
        buf[t] += u;
        __syncthreads();
    }
    if (t < NB) pstart[(size_t)bin * NB + t] = buf[t] - v;
    if (t == 511) total[bin] = buf[511];
}

// exclusive scan of totals -> boff; nstart[g] = lower_bound(batch, g); zero pooled
__global__ __launch_bounds__(1024) void k_scan_top(const int* __restrict__ total, int nb,
                                                   int* __restrict__ boff,
                                                   const int* __restrict__ batch, int N,
                                                   int* __restrict__ nstart,
                                                   float* __restrict__ pooled, int G) {
    __shared__ int buf[1024];
    int t = threadIdx.x;
    int v = (t < nb) ? total[t] : 0;
    buf[t] = v;
    __syncthreads();
    for (int off = 1; off < 1024; off <<= 1) {
        int u = (t >= off) ? buf[t - off] : 0;
        __syncthreads();
        buf[t] += u;
        __syncthreads();
    }
    if (t < nb) {
        boff[t] = buf[t] - v;
        int lo = 0, hi = N;
        while (lo < hi) { int mid = (lo + hi) >> 1; if (batch[mid] < t) lo = mid + 1; else hi = mid; }
        nstart[t] = lo;
    }
    for (int i = t; i < G * 10; i += 1024) pooled[i] = 0.f;
}

// scatter edges into graph buckets as packed int: src | (local_dst << 17)
__global__ __launch_bounds__(256) void k_bscatter(const int* __restrict__ srcE,
                                                  const int* __restrict__ dstE,
                                                  const int* __restrict__ batch,
                                                  const int* __restrict__ boff,
                                                  const int* __restrict__ pstart,
                                                  const int* __restrict__ nstart,
                                                  int E, int NB, int G, int* __restrict__ pairs) {
    __shared__ int lstart[512];
    __shared__ int lc[512];
    __shared__ int lns[512];
    int tid = threadIdx.x, b = blockIdx.x;
#pragma unroll
    for (int j = tid; j < 512; j += 256) {
        lstart[j] = (j < G) ? boff[j] + pstart[(size_t)j * NB + b] : 0;
        lns[j] = (j < G) ? nstart[j] : 0;
        lc[j] = 0;
    }
    __syncthreads();
#pragma unroll
    for (int i = 0; i < CH / 1024; ++i) {
        int eb = b * CH + (i * 256 + tid) * 4;
        if (eb + 3 < E) {
            int4 sv = *(const int4*)(srcE + eb);
            int4 dv = *(const int4*)(dstE + eb);
            int g0 = batch[dv.x], g1 = batch[dv.y], g2 = batch[dv.z], g3 = batch[dv.w];
            int p0 = atomicAdd(&lc[g0], 1);
            int p1 = atomicAdd(&lc[g1], 1);
            int p2 = atomicAdd(&lc[g2], 1);
            int p3 = atomicAdd(&lc[g3], 1);
            pairs[lstart[g0] + p0] = sv.x | ((dv.x - lns[g0]) << 17);
            pairs[lstart[g1] + p1] = sv.y | ((dv.y - lns[g1]) << 17);
            pairs[lstart[g2] + p2] = sv.z | ((dv.z - lns[g2]) << 17);
            pairs[lstart[g3] + p3] = sv.w | ((dv.w - lns[g3]) << 17);
        } else {
#pragma unroll
            for (int k = 0; k < 4; ++k)
                if (eb + k < E) {
                    int s = srcE[eb + k], d = dstE[eb + k];
                    int bin = batch[d];
                    int old = atomicAdd(&lc[bin], 1);
                    pairs[lstart[bin] + old] = s | ((d - lns[bin]) << 17);
                }
        }
    }
}

__global__ __launch_bounds__(512) void k_csr_local(const int* __restrict__ pairs,
                                                   const int* __restrict__ boff,
                                                   const int* __restrict__ batch,
                                                   int E, int N, int G,
                                                   int* __restrict__ cnt, int* __restrict__ excl,
                                                   int* __restrict__ srcs) {
    __shared__ int lcnt[512];
    __shared__ int buf[512];
    __shared__ int lcur[512];
    int g = blockIdx.x, t = threadIdx.x;
    int lo = 0, hi = N;
    while (lo < hi) { int mid = (lo + hi) >> 1; if (batch[mid] < g) lo = mid + 1; else hi = mid; }
    int ns = lo;
    hi = N;
    while (lo < hi) { int mid = (lo + hi) >> 1; if (batch[mid] < g + 1) lo = mid + 1; else hi = mid; }
    int ne = lo;
    int lnodes = ne - ns;
    int es = boff[g];
    int ee = (g + 1 < G) ? boff[g + 1] : E;

    lcnt[t] = 0;
    __syncthreads();
    for (int e = es + t; e < ee; e += 512) atomicAdd(&lcnt[pairs[e] >> 17], 1);
    __syncthreads();
    int v = lcnt[t];
    buf[t] = v;
    __syncthreads();
    for (int off = 1; off < 512; off <<= 1) {
        int u = (t >= off) ? buf[t - off] : 0;
        __syncthreads();
        buf[t] += u;
        __syncthreads();
    }
    int lex = buf[t] - v;
    lcur[t] = lex;
    if (t < lnodes) {
        cnt[ns + t] = v;
        excl[ns + t] = es + lex;
    }
    __syncthreads();
    for (int e = es + t; e < ee; e += 512) {
        int pv = pairs[e];
        int pos = atomicAdd(&lcur[pv >> 17], 1);
        srcs[es + pos] = pv & 0x1FFFF;
    }
}

// ---------------- layer 1 gather + FUSED fin1 (fast ELU) ----------------
__global__ void k_gather1(const int* __restrict__ srcs, const int* __restrict__ excl,
                          const int* __restrict__ cnt,
                          const unsigned short* __restrict__ asrcb, const float* __restrict__ adst1,
                          const unsigned short* __restrict__ h1b,
                          const float* __restrict__ b1, const float* __restrict__ W2,
                          const float* __restrict__ a_src2, const float* __restrict__ a_dst2,
                          unsigned short* __restrict__ h2b, unsigned short* __restrict__ asrc2b,
                          float* __restrict__ adst2, int N) {
    int tid = blockIdx.x * 256 + threadIdx.x;
    int wave = tid >> 6;
    int lane = threadIdx.x & 63;
    int q = lane >> 3;            // node slot 0..7
    int l = lane & 7;             // head == channel group
    int wid = wave * 8 + q;
    if (wid >= N) return;
    int c0 = l * 8;               // channels c0..c0+7

    int beg = excl[wid];
    int cw  = cnt[wid];
    const int* sp = srcs + beg;
    float adh = adst1[wid * 8 + l];

    // self-loop init on chain 0
    uint4 us = *(const uint4*)&h1b[(size_t)wid * 64 + c0];
    float4 A0a, A0b;
    A0a.x = __uint_as_float(us.x << 16); A0a.y = __uint_as_float(us.x & 0xffff0000u);
    A0a.z = __uint_as_float(us.y << 16); A0a.w = __uint_as_float(us.y & 0xffff0000u);
    A0b.x = __uint_as_float(us.z << 16); A0b.y = __uint_as_float(us.z & 0xffff0000u);
    A0b.z = __uint_as_float(us.w << 16); A0b.w = __uint_as_float(us.w & 0xffff0000u);
    float m0 = LRELU(bf2f(asrcb[wid * 8 + l]) + adh), d0 = 1.f;
    float4 Z = {0.f, 0.f, 0.f, 0.f};
    float4 A1a = Z, A1b = Z, A2a = Z, A2b = Z, A3a = Z, A3b = Z;
    float m1 = -INFINITY, d1 = 0.f;
    float m2 = -INFINITY, d2 = 0.f;
    float m3 = -INFINITY, d3 = 0.f;

    int i = 0;
    for (; i + 4 <= cw; i += 4) {
        int s0 = sp[i], s1 = sp[i + 1], s2 = sp[i + 2], s3 = sp[i + 3];
        float e0 = LRELU(bf2f(asrcb[s0 * 8 + l]) + adh);
        float e1 = LRELU(bf2f(asrcb[s1 * 8 + l]) + adh);
        float e2 = LRELU(bf2f(asrcb[s2 * 8 + l]) + adh);
        float e3 = LRELU(bf2f(asrcb[s3 * 8 + l]) + adh);
        uint4 u0 = *(const uint4*)&h1b[(size_t)s0 * 64 + c0];
        uint4 u1 = *(const uint4*)&h1b[(size_t)s1 * 64 + c0];
        uint4 u2 = *(const uint4*)&h1b[(size_t)s2 * 64 + c0];
        uint4 u3 = *(const uint4*)&h1b[(size_t)s3 * 64 + c0];
        UPD8(m0, d0, A0a, A0b, e0, u0);
        UPD8(m1, d1, A1a, A1b, e1, u1);
        UPD8(m2, d2, A2a, A2b, e2, u2);
        UPD8(m3, d3, A3a, A3b, e3, u3);
    }
    for (; i < cw; ++i) {
        int s = sp[i];
        float ev = LRELU(bf2f(asrcb[s * 8 + l]) + adh);
        uint4 uv = *(const uint4*)&h1b[(size_t)s * 64 + c0];
        UPD8(m0, d0, A0a, A0b, ev, uv);
    }
    float mM = fmaxf(fmaxf(m0, m1), fmaxf(m2, m3));
    float w0 = fexp2(m0 - mM), w1 = fexp2(m1 - mM);
    float w2 = fexp2(m2 - mM), w3 = fexp2(m3 - mM);
    float den = d0 * w0 + d1 * w1 + d2 * w2 + d3 * w3;
    float inv = 1.f / (den + 1e-16f);
    float rv[8];
    rv[0] = (A0a.x * w0 + A1a.x * w1 + A2a.x * w2 + A3a.x * w3) * inv;
    rv[1] = (A0a.y * w0 + A1a.y * w1 + A2a.y * w2 + A3a.y * w3) * inv;
    rv[2] = (A0a.z * w0 + A1a.z * w1 + A2a.z * w2 + A3a.z * w3) * inv;
    rv[3] = (A0a.w * w0 + A1a.w * w1 + A2a.w * w2 + A3a.w * w3) * inv;
    rv[4] = (A0b.x * w0 + A1b.x * w1 + A2b.x * w2 + A3b.x * w3) * inv;
    rv[5] = (A0b.y * w0 + A1b.y * w1 + A2b.y * w2 + A3b.y * w3) * inv;
    rv[6] = (A0b.z * w0 + A1b.z * w1 + A2b.z * w2 + A3b.z * w3) * inv;
    rv[7] = (A0b.w * w0 + A1b.w * w1 + A2b.w * w2 + A3b.w * w3) * inv;

    // ---- fused fin1: felu(rv + b1) @ W2, 8-lane butterfly reduce ----
    float accj[10];
#pragma unroll
    for (int j = 0; j < 10; ++j) accj[j] = 0.f;
#pragma unroll
    for (int t = 0; t < 8; ++t) {
        float r = felu(rv[t] + b1[c0 + t]);
        const float* wr = W2 + (c0 + t) * 10;
#pragma unroll
        for (int j = 0; j < 10; ++j) accj[j] = fmaf(r, wr[j], accj[j]);
    }
#pragma unroll
    for (int mask = 1; mask <= 4; mask <<= 1)
#pragma unroll
        for (int j = 0; j < 10; ++j) accj[j] += __shfl_xor(accj[j], mask);

    if (l == 0) {
        float s = 0.f, d = 0.f;
        unsigned pw[5];
#pragma unroll
        for (int j = 0; j < 10; j += 2) {
            s = fmaf(accj[j], a_src2[j], s);     d = fmaf(accj[j], a_dst2[j], d);
            s = fmaf(accj[j+1], a_src2[j+1], s); d = fmaf(accj[j+1], a_dst2[j+1], d);
            pw[j >> 1] = (unsigned)f2bf(accj[j]) | ((unsigned)f2bf(accj[j+1]) << 16);
        }
        unsigned* hw = (unsigned*)&h2b[(size_t)wid * 10];
#pragma unroll
        for (int j = 0; j < 5; ++j) hw[j] = pw[j];
        asrc2b[wid] = f2bf(s * L2E);
        adst2[wid] = d * L2E;
    }
}

// ---------------- layer 2 gather + FUSED pooling ----------------
// 4 nodes/wave, 16 lanes/node; per-node result goes to LDS; 10 threads
// run-length-merge by graph and atomicAdd into pooled[G][10].
__global__ void k_gather2p(const int* __restrict__ srcs, const int* __restrict__ excl,
                           const int* __restrict__ cnt,
                           const unsigned short* __restrict__ asrc2b, const float* __restrict__ adst2,
                           const unsigned short* __restrict__ h2b,
                           const int* __restrict__ batch, float* __restrict__ pooled, int N) {
    __shared__ float lval[16][10];
    __shared__ int lgr[16];
    int tid = blockIdx.x * 256 + threadIdx.x;
    int wave = tid >> 6;
    int lane = threadIdx.x & 63;
    int q = lane >> 4;
    int l = lane & 15;
    int wid = wave * 4 + q;
    bool valid = wid < N;
    if (threadIdx.x < 16) lgr[threadIdx.x] = -1;
    __syncthreads();

    if (valid) {
        int beg = excl[wid];
        int cw  = cnt[wid];
        const int* sp = srcs + beg;
        float adn = adst2[wid];
        bool ld = l < 10;

        float m0 = LRELU(bf2f(asrc2b[wid]) + adn), d0 = 1.f;
        float a0 = ld ? bf2f(h2b[(size_t)wid * 10 + l]) : 0.f;
        float m1 = -INFINITY, d1 = 0.f, a1 = 0.f;
        float m2 = -INFINITY, d2 = 0.f, a2 = 0.f;
        float m3 = -INFINITY, d3 = 0.f, a3 = 0.f;

        int i = 0;
        for (; i + 4 <= cw; i += 4) {
            int s0 = sp[i], s1 = sp[i + 1], s2 = sp[i + 2], s3 = sp[i + 3];
            float e0 = LRELU(bf2f(asrc2b[s0]) + adn);
            float e1 = LRELU(bf2f(asrc2b[s1]) + adn);
            float e2 = LRELU(bf2f(asrc2b[s2]) + adn);
            float e3 = LRELU(bf2f(asrc2b[s3]) + adn);
            float g0 = ld ? bf2f(h2b[(size_t)s0 * 10 + l]) : 0.f;
            float g1 = ld ? bf2f(h2b[(size_t)s1 * 10 + l]) : 0.f;
            float g2 = ld ? bf2f(h2b[(size_t)s2 * 10 + l]) : 0.f;
            float g3 = ld ? bf2f(h2b[(size_t)s3 * 10 + l]) : 0.f;
            UPD1(m0, d0, a0, e0, g0);
            UPD1(m1, d1, a1, e1, g1);
            UPD1(m2, d2, a2, e2, g2);
            UPD1(m3, d3, a3, e3, g3);
        }
        for (; i < cw; ++i) {
            int s = sp[i];
            float ev = LRELU(bf2f(asrc2b[s]) + adn);
            float gv = ld ? bf2f(h2b[(size_t)s * 10 + l]) : 0.f;
            UPD1(m0, d0, a0, ev, gv);
        }
        float mM = fmaxf(fmaxf(m0, m1), fmaxf(m2, m3));
        float w0 = fexp2(m0 - mM), w1 = fexp2(m1 - mM);
        float w2 = fexp2(m2 - mM), w3 = fexp2(m3 - mM);
        float den = d0 * w0 + d1 * w1 + d2 * w2 + d3 * w3;
        float acc = a0 * w0 + a1 * w1 + a2 * w2 + a3 * w3;
        int slot = wid & 15;
        if (ld) lval[slot][l] = acc / (den + 1e-16f);
        if (l == 0) lgr[slot] = batch[wid];
    }
    __syncthreads();
    // merge consecutive same-graph slots, one atomicAdd per (graph, ch) run
    if (threadIdx.x < 10) {
        int c = threadIdx.x;
        float run = 0.f;
        int curg = -1;
        for (int s = 0; s < 16; ++s) {
            int g = lgr[s];
            if (g < 0) continue;
            if (g != curg) {
                if (curg >= 0) atomicAdd(&pooled[curg * 10 + c], run);
                curg = g; run = 0.f;
            }
            run += lval[s][c];
        }
        if (curg >= 0) atomicAdd(&pooled[curg * 10 + c], run);
    }
}

// ---------------- final: mean (+b2) + log_softmax; thread per graph ----------------
__global__ __launch_bounds__(512) void k_final(const float* __restrict__ pooled,
                                               const float* __restrict__ b2,
                                               const int* __restrict__ nstart,
                                               float* __restrict__ out, int N, int G) {
    int t = threadIdx.x + blockIdx.x * 512;
    if (t >= G) return;
    int c = ((t + 1 < G) ? nstart[t + 1] : N) - nstart[t];
    float cf = (float)c;
    float invc = 1.f / fmaxf(cf, 1.f);
    float v[10], m = -1e30f;
#pragma unroll
    for (int j = 0; j < 10; ++j) {
        v[j] = (pooled[(size_t)t * 10 + j] + cf * b2[j]) * invc;
        m = fmaxf(m, v[j]);
    }
    float ssum = 0.f;
#pragma unroll
    for (int j = 0; j < 10; ++j) ssum += expf(v[j] - m);
    float ls = logf(ssum);
#pragma unroll
    for (int j = 0; j < 10; ++j) out[(size_t)t * 10 + j] = v[j] - m - ls;
}

extern "C" void kernel_launch(void* const* d_in, const int* in_sizes, int n_in,
                              void* d_out, int out_size, void* d_ws, size_t ws_size,
                              hipStream_t stream) {
    const float* x     = (const float*)d_in[0];
    const int*   ei    = (const int*)d_in[1];
    const int*   batch = (const int*)d_in[2];
    const float* W1    = (const float*)d_in[3];
    const float* as1w  = (const float*)d_in[4];
    const float* ad1w  = (const float*)d_in[5];
    const float* b1    = (const float*)d_in[6];
    const float* W2    = (const float*)d_in[7];
    const float* as2w  = (const float*)d_in[8];
    const float* ad2w  = (const float*)d_in[9];
    const float* b2    = (const float*)d_in[10];

    const int N  = in_sizes[0] / 128;
    const int E  = in_sizes[1] / 2;
    const int G  = out_size / 10;
    const int* srcE = ei;
    const int* dstE = ei + E;

    auto cdiv = [](long long a, long long b) { return (int)((a + b - 1) / b); };
    const int NB = cdiv(E, CH);

    // ---- workspace layout ----
    size_t Nz = (size_t)N;
    unsigned short* h1b = (unsigned short*)d_ws;        // N*64 bf16
    unsigned short* asrc1b = h1b + Nz * 64;             // N*8 bf16
    float* adst1 = (float*)(asrc1b + Nz * 8);           // N*8 f32
    unsigned short* h2b = (unsigned short*)(adst1 + Nz * 8); // N*10 bf16
    unsigned short* asrc2b = h2b + Nz * 10;             // N bf16
    float* adst2 = (float*)(asrc2b + Nz + (Nz & 1));    // N f32 (align 4B)
    int* pairsA  = (int*)(adst2 + Nz);                  // E (packed src|ldst<<17)
    int* cntA    = pairsA + (size_t)E;                  // N
    int* exclA   = cntA + Nz;                           // N
    int* srcsA   = exclA + Nz;                          // E
    int* bhA     = srcsA + E;                           // 512*NB
    int* pstartA = bhA + (size_t)512 * NB;              // 512*NB
    int* totalA  = pstartA + (size_t)512 * NB;          // 512
    int* boffA   = totalA + 512;                        // 512
    int* nstartA = boffA + 512;                         // 512
    float* pooledA = (float*)(nstartA + 512);           // G*10

    const int B = 256;

    // layer-1 MFMA GEMM with fused alpha dots
    int ntiles = cdiv(N, 16);
    int gB = ntiles < 2048 ? ntiles : 2048;
    k_gemm1_mfma<<<gB, B, 0, stream>>>(x, W1, as1w, ad1w, h1b, asrc1b, adst1, N, ntiles);

    // CSR build (two-kernel scan; scan_top also zeroes pooled)
    k_bhist<<<NB, B, 0, stream>>>(dstE, batch, E, NB, G, bhA);
    k_mscan<<<512, 512, 0, stream>>>(bhA, NB, pstartA, totalA);
    k_scan_top<<<1, 1024, 0, stream>>>(totalA, G, boffA, batch, N, nstartA, pooledA, G);
    k_bscatter<<<NB, B, 0, stream>>>(srcE, dstE, batch, boffA, pstartA, nstartA, E, NB, G, pairsA);
    k_csr_local<<<G, 512, 0, stream>>>(pairsA, boffA, batch, E, N, G, cntA, exclA, srcsA);

    // layer 1 gather + fused fin1: 32 nodes/block (8/wave), 8ch/lane
    k_gather1<<<cdiv(N, 32), B, 0, stream>>>(srcsA, exclA, cntA, asrc1b, adst1, h1b,
                                             b1, W2, as2w, ad2w, h2b, asrc2b, adst2, N);

    // layer 2 gather + fused pooling
    k_gather2p<<<cdiv(N, 16), B, 0, stream>>>(srcsA, exclA, cntA, asrc2b, adst2, h2b,
                                              batch, pooledA, N);

    // mean + log_softmax
    k_final<<<cdiv(G, 512), 512, 0, stream>>>(pooledA, b2, nstartA, (float*)d_out, N, G);
}